// Round 13
// baseline (1515.222 us; speedup 1.0000x reference)
//
#include <hip/hip_runtime.h>

typedef _Float16 f16x8 __attribute__((ext_vector_type(8)));
typedef short    s16x8 __attribute__((ext_vector_type(8)));
typedef float    f32x4 __attribute__((ext_vector_type(4)));

__device__ __forceinline__ unsigned short f2bf(float f) {
  union { float f; unsigned u; } x; x.f = f;
  unsigned r = (x.u + 0x7fffu + ((x.u >> 16) & 1u)) >> 16;  // RNE
  return (unsigned short)r;
}
__device__ __forceinline__ float bf2f(unsigned short u) {
  union { unsigned u; float f; } x; x.u = ((unsigned)u) << 16; return x.f;
}

// ================= weight prepack: OIHW fp32 -> [oc][3*KPAD] split hi/lo f16 =================
__global__ void prepack_w(const float* __restrict__ w, _Float16* __restrict__ ph,
                          _Float16* __restrict__ pl, int COUT, int CIN, int KPAD)
{
  const int idx = blockIdx.x * 256 + threadIdx.x;
  const int KTOT = 3 * KPAD;
  if (idx >= COUT * KTOT) return;
  const int oc = idx / KTOT;
  const int rem = idx - oc * KTOT;
  const int y = rem / KPAD;
  const int kk = rem - y * KPAD;
  float v = 0.f;
  if (kk < 3 * CIN) {
    const int tx = kk / CIN;
    const int ic = kk - tx * CIN;
    v = w[((size_t)oc * CIN + ic) * 9 + y * 3 + tx];
  }
  const _Float16 h = (_Float16)v;
  ph[idx] = h;
  pl[idx] = (_Float16)((v - (float)h) * 2048.0f);
}

// ================= conv1: CIN=1, VALU fp32, NHWC split-f16 out =================
__global__ __launch_bounds__(256)
void conv1_k(const float* __restrict__ obs, const float* __restrict__ w,
             const float* __restrict__ bias, _Float16* __restrict__ outh,
             _Float16* __restrict__ outl)
{
  const int rg = blockIdx.x;
  const int b = blockIdx.y;
  const int tid = threadIdx.x;
  const int lr = tid >> 6;
  const int col = tid & 63;
  __shared__ float xs[6][66];
  __shared__ float wb[9][16];
  for (int idx = tid; idx < 6 * 66; idx += 256) {
    const int r = idx / 66, c = idx - (idx / 66) * 66;
    const int gr = rg * 4 - 1 + r, gc = c - 1;
    xs[r][c] = (gr >= 0 && gr < 64 && gc >= 0 && gc < 64)
                   ? obs[(size_t)b * 4096 + gr * 64 + gc] : 0.f;
  }
  if (tid < 144) wb[tid / 16][tid & 15] = w[(tid & 15) * 9 + tid / 16];
  __syncthreads();
  float acc[16];
#pragma unroll
  for (int o = 0; o < 16; ++o) acc[o] = bias[o];
#pragma unroll
  for (int ty = 0; ty < 3; ++ty)
#pragma unroll
    for (int tx = 0; tx < 3; ++tx) {
      const float x = xs[lr + ty][col + tx];
#pragma unroll
      for (int o = 0; o < 16; ++o) acc[o] = fmaf(x, wb[ty * 3 + tx][o], acc[o]);
    }
  const size_t base = ((size_t)(b * 64 + rg * 4 + lr) * 64 + col) * 16;
#pragma unroll
  for (int o = 0; o < 16; ++o) {
    const float v = fmaxf(acc[o], 0.f);
    const _Float16 h = (_Float16)v;
    outh[base + o] = h;
    outl[base + o] = (_Float16)((v - (float)h) * 2048.0f);
  }
}

// ================= conv MFMA: NHWC shift-GEMM, split-f16 3-term =================
// NCHW_OUT: epilogue transposes via LDS, stores bf16 hi + bf16 lo (unscaled) for fc1
template<int CIN, int COUT, bool NCHW_OUT>
__global__ __launch_bounds__(256)
void conv_mfma(const _Float16* __restrict__ inh, const _Float16* __restrict__ inl,
               const _Float16* __restrict__ wph, const _Float16* __restrict__ wpl,
               const float* __restrict__ bias,
               unsigned short* __restrict__ outh, unsigned short* __restrict__ outl)
{
  constexpr int KFX = (3 * CIN + 31) / 32;
  constexpr int KPAD = KFX * 32;
  constexpr int KTOT = 3 * KPAD;
  constexpr int CP = CIN + 8;
  constexpr int NF = COUT / 32;
  constexpr int STO = NCHW_OUT ? COUT : 1;
  constexpr int STP = NCHW_OUT ? 136 : 8;
  const int rp = blockIdx.x;
  const int b  = blockIdx.y;
  const int r0 = rp * 2;
  const int tid = threadIdx.x;
  const int lane = tid & 63;
  const int wid = tid >> 6;
  const int wm = wid >> 1;
  const int wn = wid & 1;

  __shared__ _Float16 xh[4][68][CP];
  __shared__ _Float16 xl[4][68][CP];
  __shared__ unsigned short st_h[STO][STP];
  __shared__ unsigned short st_l[STO][STP];

  constexpr int CH = CIN / 8;
  for (int idx = tid; idx < 4 * 68 * CH; idx += 256) {
    const int r = idx / (68 * CH);
    const int rem = idx - r * 68 * CH;
    const int hc = rem / CH;
    const int ch = rem - hc * CH;
    const int gr = r0 - 1 + r;
    const int gc = hc - 1;
    uint4 vh = {0, 0, 0, 0}, vl = {0, 0, 0, 0};
    if (gr >= 0 && gr < 64 && gc >= 0 && gc < 64) {
      const size_t base = ((size_t)(b * 64 + gr) * 64 + gc) * CIN + ch * 8;
      vh = *(const uint4*)(inh + base);
      vl = *(const uint4*)(inl + base);
    }
    *(uint4*)&xh[r][hc][ch * 8] = vh;
    *(uint4*)&xl[r][hc][ch * 8] = vl;
  }
  __syncthreads();

  f32x4 accm[4][NF];
  f32x4 accc[4][NF];
#pragma unroll
  for (int mf = 0; mf < 4; ++mf)
#pragma unroll
    for (int nf = 0; nf < NF; ++nf) { accm[mf][nf] = {}; accc[mf][nf] = {}; }

  const int lm = lane & 15;
  const int ch8 = (lane >> 4) * 8;

#pragma unroll
  for (int kf = 0; kf < 3 * KFX; ++kf) {
    const int y = kf / KFX;
    const int fx = kf - y * KFX;
    const int kk = fx * 32 + ch8;
    f16x8 bh[NF], bl[NF];
#pragma unroll
    for (int nf = 0; nf < NF; ++nf) {
      const int oc = wn * (16 * NF) + nf * 16 + lm;
      bh[nf] = *(const f16x8*)(wph + (size_t)oc * KTOT + kf * 32 + ch8);
      bl[nf] = *(const f16x8*)(wpl + (size_t)oc * KTOT + kf * 32 + ch8);
    }
#pragma unroll
    for (int mf = 0; mf < 4; ++mf) {
      const int col = mf * 16 + lm;
      const f16x8 ah = *(const f16x8*)&xh[wm + y][col + kk / CIN][kk % CIN];
      const f16x8 al = *(const f16x8*)&xl[wm + y][col + kk / CIN][kk % CIN];
#pragma unroll
      for (int nf = 0; nf < NF; ++nf) {
        accm[mf][nf] = __builtin_amdgcn_mfma_f32_16x16x32_f16(ah, bh[nf], accm[mf][nf], 0, 0, 0);
        accc[mf][nf] = __builtin_amdgcn_mfma_f32_16x16x32_f16(ah, bl[nf], accc[mf][nf], 0, 0, 0);
        accc[mf][nf] = __builtin_amdgcn_mfma_f32_16x16x32_f16(al, bh[nf], accc[mf][nf], 0, 0, 0);
      }
    }
  }

  if constexpr (NCHW_OUT) {
    // ---- stage bf16(hi) + bf16(lo, unscaled) to LDS, then contiguous NCHW stores ----
#pragma unroll
    for (int nf = 0; nf < NF; ++nf) {
      const int oc = wn * (16 * NF) + nf * 16 + lm;
      const float bv = bias[oc];
#pragma unroll
      for (int mf = 0; mf < 4; ++mf) {
        unsigned short hv[4], lv[4];
#pragma unroll
        for (int r = 0; r < 4; ++r) {
          const float v = fmaxf(accm[mf][nf][r] + accc[mf][nf][r] * (1.0f / 2048.0f) + bv, 0.f);
          const unsigned short hb = f2bf(v);
          hv[r] = hb;
          lv[r] = f2bf(v - bf2f(hb));
        }
        const int px = wm * 64 + mf * 16 + (lane >> 4) * 4;
        *(ushort4*)&st_h[oc][px] = make_ushort4(hv[0], hv[1], hv[2], hv[3]);
        *(ushort4*)&st_l[oc][px] = make_ushort4(lv[0], lv[1], lv[2], lv[3]);
      }
    }
    __syncthreads();
    const int oc2 = tid >> 2;
    const int seg = tid & 3;
    const size_t gb = ((size_t)b * COUT + oc2) * 4096 + r0 * 64 + seg * 32;
#pragma unroll
    for (int j2 = 0; j2 < 4; ++j2) {
      *(uint4*)(outh + gb + j2 * 8) = *(const uint4*)&st_h[oc2][seg * 32 + j2 * 8];
      *(uint4*)(outl + gb + j2 * 8) = *(const uint4*)&st_l[oc2][seg * 32 + j2 * 8];
    }
  } else {
    const int orow = r0 + wm;
#pragma unroll
    for (int nf = 0; nf < NF; ++nf) {
      const int oc = wn * (16 * NF) + nf * 16 + lm;
      const float bv = bias[oc];
#pragma unroll
      for (int mf = 0; mf < 4; ++mf) {
#pragma unroll
        for (int r = 0; r < 4; ++r) {
          const int x = mf * 16 + (lane >> 4) * 4 + r;
          const float v = fmaxf(accm[mf][nf][r] + accc[mf][nf][r] * (1.0f / 2048.0f) + bv, 0.f);
          const _Float16 h = (_Float16)v;
          union { _Float16 f; unsigned short u; } ch_, cl_;
          ch_.f = h;
          cl_.f = (_Float16)((v - (float)h) * 2048.0f);
          const size_t oi = ((size_t)(b * 64 + orow) * 64 + x) * COUT + oc;
          outh[oi] = ch_.u;
          outl[oi] = cl_.u;
        }
      }
    }
  }
}

// ================= fc1 v13: v11 + 3-phase interleave + counted vmcnt + setprio =================
// grid(64 sk, 4 nt) = 256 blocks. block 512 = 8 waves (4M x 2N), wave 64x128.
// K-slice 4096, BK=32, 128 its. LDS 128 KB. wrA/wrB register dbuf for W.
__global__ __launch_bounds__(512, 2)
void fc1_gemm_v13(const unsigned short* __restrict__ Ahi, const unsigned short* __restrict__ Alo,
                  const float* __restrict__ W, float* __restrict__ P)
{
  const int sk = blockIdx.x;
  const int nt = blockIdx.y;
  const int nc0 = nt * 256;
  const int tid = threadIdx.x;
  const int lane = tid & 63;
  const int wid = tid >> 6;
  const int wm = wid >> 1;          // 0..3
  const int wn = wid & 1;           // 0..1

  __shared__ unsigned short Ah[2][256][32];   // 32 KB
  __shared__ unsigned short Al[2][256][32];   // 32 KB
  __shared__ unsigned short Bh[2][256][32];   // 32 KB
  __shared__ unsigned short Bl[2][256][32];   // 32 KB

  f32x4 acc[4][8] = {};

  const int nl = tid & 255;         // B col 0..255
  const int kq = tid >> 8;          // 0..1 -> k rows kq*16..+16
  const int q = lane >> 4;          // fragment k-slot

  const size_t kbase = (size_t)sk * 4096;
  constexpr int NIT = 128;

  // ---- A DMA mapping (v4-verbatim): wave wid stages rows wid*32..+32 ----
  const int Rbase = wid * 32;
  const int lrow0 = Rbase + (lane >> 2);
  const int lrow1 = Rbase + 16 + (lane >> 2);
  const int sd = lane & 3;
  const int ssrc0 = sd ^ ((lrow0 >> 1) & 3);
  const int ssrc1 = sd ^ ((lrow1 >> 1) & 3);
  const size_t goff0 = (size_t)lrow0 * 262144 + ssrc0 * 8;
  const size_t goff1 = (size_t)lrow1 * 262144 + ssrc1 * 8;

#define ISSUE_A(p, k0)                                                                     \
  {                                                                                        \
    __builtin_amdgcn_global_load_lds(                                                      \
        (const __attribute__((address_space(1))) unsigned int*)(Ahi + goff0 + (k0)),       \
        (__attribute__((address_space(3))) unsigned int*)&Ah[p][Rbase][0], 16, 0, 0);      \
    __builtin_amdgcn_global_load_lds(                                                      \
        (const __attribute__((address_space(1))) unsigned int*)(Ahi + goff1 + (k0)),       \
        (__attribute__((address_space(3))) unsigned int*)&Ah[p][Rbase + 16][0], 16, 0, 0); \
    __builtin_amdgcn_global_load_lds(                                                      \
        (const __attribute__((address_space(1))) unsigned int*)(Alo + goff0 + (k0)),       \
        (__attribute__((address_space(3))) unsigned int*)&Al[p][Rbase][0], 16, 0, 0);      \
    __builtin_amdgcn_global_load_lds(                                                      \
        (const __attribute__((address_space(1))) unsigned int*)(Alo + goff1 + (k0)),       \
        (__attribute__((address_space(3))) unsigned int*)&Al[p][Rbase + 16][0], 16, 0, 0); \
  }

#define LOAD_W(k0, wr)                                                      \
  {                                                                         \
    const size_t jb = (k0) + kq * 16;                                       \
    _Pragma("unroll") for (int i = 0; i < 16; ++i) {                        \
      wr[i] = W[(jb + i) * 1024 + nc0 + nl];                                \
    }                                                                       \
  }

#define WRITE_B(p, wr)                                                      \
  {                                                                         \
    _Pragma("unroll") for (int h2 = 0; h2 < 2; ++h2) {                      \
      s16x8 hv, lv;                                                         \
      _Pragma("unroll") for (int j = 0; j < 8; ++j) {                       \
        const float f = wr[h2 * 8 + j];                                     \
        const unsigned short hb = f2bf(f);                                  \
        hv[j] = (short)hb;                                                  \
        lv[j] = (short)f2bf(f - bf2f(hb));                                  \
      }                                                                     \
      const int sw = (kq * 2 + h2) ^ ((nl >> 1) & 3);                       \
      *(s16x8*)&Bh[p][nl][sw * 8] = hv;                                     \
      *(s16x8*)&Bl[p][nl][sw * 8] = lv;                                     \
    }                                                                       \
  }

#define READ_A(p, ah, al)                                                   \
  _Pragma("unroll") for (int mf = 0; mf < 4; ++mf) {                        \
    const int r = wm * 64 + mf * 16 + (lane & 15);                          \
    const int s = (q ^ ((r >> 1) & 3)) * 8;                                 \
    ah[mf] = *(const s16x8*)&Ah[p][r][s];                                   \
    al[mf] = *(const s16x8*)&Al[p][r][s];                                   \
  }

#define READ_B(p, hfc, bh, bl)                                              \
  _Pragma("unroll") for (int nf = 0; nf < 4; ++nf) {                        \
    const int n = wn * 128 + ((hfc) * 4 + nf) * 16 + (lane & 15);           \
    const int s = (q ^ ((n >> 1) & 3)) * 8;                                 \
    bh[nf] = *(const s16x8*)&Bh[p][n][s];                                   \
    bl[nf] = *(const s16x8*)&Bl[p][n][s];                                   \
  }

#define MFMA_HF(hfc, ah, al, bh, bl)                                        \
  __builtin_amdgcn_s_setprio(1);                                            \
  _Pragma("unroll") for (int mf = 0; mf < 4; ++mf)                          \
    _Pragma("unroll") for (int nf = 0; nf < 4; ++nf) {                      \
      acc[mf][(hfc)*4+nf] = __builtin_amdgcn_mfma_f32_16x16x32_bf16(ah[mf], bh[nf], acc[mf][(hfc)*4+nf], 0, 0, 0); \
      acc[mf][(hfc)*4+nf] = __builtin_amdgcn_mfma_f32_16x16x32_bf16(al[mf], bh[nf], acc[mf][(hfc)*4+nf], 0, 0, 0); \
      acc[mf][(hfc)*4+nf] = __builtin_amdgcn_mfma_f32_16x16x32_bf16(ah[mf], bl[nf], acc[mf][(hfc)*4+nf], 0, 0, 0); \
    }                                                                       \
  __builtin_amdgcn_s_setprio(0);

  // One iteration, 3 phases. Safety invariants:
  //  S1-barrier: all waves finished reading A[cur] (and B hf0)  -> S3 DMA into A[cur] safe
  //  S2-barrier: all waves finished ALL reads of [cur]
  //  S3: issue A-DMA(it+2)+W(it+2) BEFORE WRITE_B -> implicit wr wait = counted vmcnt(20),
  //      which also drains DMA(it+1) (older) -> next iter's A[cur^1] reads safe after barrier.
#define ITER(cur, wrCur, wrNext, it)                                        \
  {                                                                         \
    s16x8 ah[4], al[4], bh0[4], bl0[4], bh1[4], bl1[4];                     \
    READ_A(cur, ah, al);                                                    \
    READ_B(cur, 0, bh0, bl0);                                               \
    asm volatile("s_waitcnt lgkmcnt(0)\n\ts_barrier" ::: "memory");         \
    READ_B(cur, 1, bh1, bl1);                                               \
    MFMA_HF(0, ah, al, bh0, bl0);                                           \
    asm volatile("s_waitcnt lgkmcnt(0)\n\ts_barrier" ::: "memory");         \
    if ((it) + 2 < NIT) {                                                   \
      const size_t k2 = kbase + (size_t)((it) + 2) * 32;                    \
      ISSUE_A(cur, k2);                                                     \
      LOAD_W(k2, wrNext);                                                   \
    }                                                                       \
    if ((it) + 1 < NIT) WRITE_B(cur ^ 1, wrCur);                            \
    MFMA_HF(1, ah, al, bh1, bl1);                                           \
    asm volatile("s_waitcnt lgkmcnt(0)\n\ts_barrier" ::: "memory");         \
  }

  float wrA[16], wrB[16];

  // ---- prologue: stage tile0 (A+B), keep tile1 loads in flight across barrier ----
  LOAD_W(kbase, wrA);              // W(0): 16 (oldest)
  ISSUE_A(0, kbase);               // DMA(0): 4
  WRITE_B(0, wrA);                 // waits W(0) -> vmcnt(4): DMA(0) stays outstanding
  ISSUE_A(1, kbase + 32);          // DMA(1): 4
  LOAD_W(kbase + 32, wrA);         // W(1): 16 -> wrA is wrCur for iter 0
  // outstanding: DMA(0)=4 (oldest) + DMA(1)=4 + W(1)=16; keep 20 newest, drain DMA(0)
  asm volatile("s_waitcnt vmcnt(20)\n\ts_waitcnt lgkmcnt(0)\n\ts_barrier" ::: "memory");

  for (int it = 0; it < NIT; it += 2) {
    ITER(0, wrA, wrB, it);
    ITER(1, wrB, wrA, it + 1);
  }
#undef ISSUE_A
#undef LOAD_W
#undef WRITE_B
#undef READ_A
#undef READ_B
#undef MFMA_HF
#undef ITER

  // epilogue: C/D layout col=lane&15, row=(lane>>4)*4+r
#pragma unroll
  for (int mf = 0; mf < 4; ++mf) {
    const int rbase = wm * 64 + mf * 16 + ((lane >> 4) << 2);
#pragma unroll
    for (int nf = 0; nf < 8; ++nf) {
      const int c = nc0 + wn * 128 + nf * 16 + (lane & 15);
#pragma unroll
      for (int r = 0; r < 4; ++r)
        P[((size_t)sk * 256 + rbase + r) * 1024 + c] = acc[mf][nf][r];
    }
  }
}

// ================= fc1 reduce (64 partials) =================
__global__ __launch_bounds__(256)
void fc1_reduce(const float* __restrict__ P, const float* __restrict__ bias,
                float* __restrict__ s1)
{
  const int idx = blockIdx.x * 256 + threadIdx.x;
  const int n = idx & 1023;
  float a = bias[n];
#pragma unroll 8
  for (int sk = 0; sk < 64; ++sk) a += P[(size_t)sk * 262144 + idx];
  s1[idx] = fmaxf(a, 0.f);
}

// ================= fc2 =================
__global__ __launch_bounds__(256)
void fc2_k(const float* __restrict__ s1, const float* __restrict__ w,
           const float* __restrict__ b, float* __restrict__ s2)
{
  const int bb = blockIdx.x;
  const int t = threadIdx.x;
  __shared__ float xr[1024];
  for (int i = t; i < 1024; i += 256) xr[i] = s1[bb * 1024 + i];
  __syncthreads();
  float a0 = b[t], a1 = 0.f, a2 = 0.f, a3 = 0.f;
#pragma unroll 4
  for (int k = 0; k < 1024; k += 4) {
    a0 += xr[k + 0] * w[(k + 0) * 256 + t];
    a1 += xr[k + 1] * w[(k + 1) * 256 + t];
    a2 += xr[k + 2] * w[(k + 2) * 256 + t];
    a3 += xr[k + 3] * w[(k + 3) * 256 + t];
  }
  s2[bb * 256 + t] = fmaxf(a0 + a1 + a2 + a3, 0.f);
}

// ================= gate =================
__global__ __launch_bounds__(64)
void gate_k(const float* __restrict__ s2, const float* __restrict__ gw,
            const float* __restrict__ gb, float* __restrict__ gate_out,
            int* __restrict__ topi, float* __restrict__ topv)
{
  const int bb = blockIdx.x;
  const int l = threadIdx.x;
  float part[8] = {};
  for (int k = l; k < 256; k += 64) {
    const float x = s2[bb * 256 + k];
#pragma unroll
    for (int e = 0; e < 8; ++e) part[e] += x * gw[k * 8 + e];
  }
#pragma unroll
  for (int off = 32; off > 0; off >>= 1)
#pragma unroll
    for (int e = 0; e < 8; ++e) part[e] += __shfl_down(part[e], off);

  if (l == 0) {
    float lg[8];
    float m = -1e30f;
#pragma unroll
    for (int e = 0; e < 8; ++e) { lg[e] = part[e] + gb[e]; m = fmaxf(m, lg[e]); }
    float s = 0.f;
    float p[8];
#pragma unroll
    for (int e = 0; e < 8; ++e) { p[e] = expf(lg[e] - m); s += p[e]; }
#pragma unroll
    for (int e = 0; e < 8; ++e) { p[e] = p[e] / s; gate_out[bb * 8 + e] = p[e]; }
    int i0 = 0;
#pragma unroll
    for (int e = 1; e < 8; ++e) if (p[e] > p[i0]) i0 = e;
    int i1 = (i0 == 0) ? 1 : 0;
#pragma unroll
    for (int e = 0; e < 8; ++e) if (e != i0 && p[e] > p[i1]) i1 = e;
    const float v0 = p[i0], v1 = p[i1];
    topi[bb * 2 + 0] = i0; topi[bb * 2 + 1] = i1;
    topv[bb * 2 + 0] = v0 / (v0 + v1); topv[bb * 2 + 1] = v1 / (v0 + v1);
  }
}

// ================= experts =================
__global__ __launch_bounds__(256)
void expert_k(const float* __restrict__ s2, const float* __restrict__ w1,
              const float* __restrict__ b1, const float* __restrict__ w2,
              const float* __restrict__ b2, const int* __restrict__ topi,
              const float* __restrict__ topv, float* __restrict__ out)
{
  const int bb = blockIdx.x;
  const int t = threadIdx.x;
  __shared__ float xr[256];
  __shared__ float eh[512];
  __shared__ float partial[18][8];
  xr[t] = s2[bb * 256 + t];
  float logit = 0.f;
  for (int kk = 0; kk < 2; ++kk) {
    __syncthreads();
    const int e = topi[bb * 2 + kk];
    const float tv = topv[bb * 2 + kk];
    const float* W1 = w1 + (size_t)e * 256 * 512;
    float a0 = b1[e * 512 + t], a1 = b1[e * 512 + 256 + t];
#pragma unroll 4
    for (int k = 0; k < 256; ++k) {
      const float x = xr[k];
      a0 = fmaf(x, W1[k * 512 + t], a0);
      a1 = fmaf(x, W1[k * 512 + 256 + t], a1);
    }
    eh[t] = fmaxf(a0, 0.f);
    eh[256 + t] = fmaxf(a1, 0.f);
    __syncthreads();
    if (t < 144) {
      const int a = t >> 3, q2 = t & 7;
      const float* W2 = w2 + (size_t)e * 512 * 18;
      float pp = 0.f;
      for (int h = q2 * 64; h < q2 * 64 + 64; ++h) pp = fmaf(eh[h], W2[h * 18 + a], pp);
      partial[a][q2] = pp;
    }
    __syncthreads();
    if (t < 18) {
      float s = b2[e * 18 + t];
#pragma unroll
      for (int q2 = 0; q2 < 8; ++q2) s += partial[t][q2];
      logit = fmaf(tv, s, logit);
    }
  }
  if (t < 18) out[bb * 18 + t] = logit;
}

// ================= launch =================
extern "C" void kernel_launch(void* const* d_in, const int* in_sizes, int n_in,
                              void* d_out, int out_size, void* d_ws, size_t ws_size,
                              hipStream_t stream) {
  const float* obs     = (const float*)d_in[0];
  const float* conv1_w = (const float*)d_in[1];
  const float* conv1_b = (const float*)d_in[2];
  const float* conv2_w = (const float*)d_in[3];
  const float* conv2_b = (const float*)d_in[4];
  const float* conv3_w = (const float*)d_in[5];
  const float* conv3_b = (const float*)d_in[6];
  const float* fc1_w   = (const float*)d_in[7];
  const float* fc1_b   = (const float*)d_in[8];
  const float* fc2_w   = (const float*)d_in[9];
  const float* fc2_b   = (const float*)d_in[10];
  const float* gate_w  = (const float*)d_in[11];
  const float* gate_b  = (const float*)d_in[12];
  const float* exp_w1  = (const float*)d_in[13];
  const float* exp_b1  = (const float*)d_in[14];
  const float* exp_w2  = (const float*)d_in[15];
  const float* exp_b2  = (const float*)d_in[16];

  char* ws = (char*)d_ws;
  const size_t MB = 1ull << 20;
  const size_t KB = 1ull << 10;
  _Float16*       act1h = (_Float16*)(ws);                 // 32 MB [256][64][64][16] NHWC f16
  _Float16*       act1l = (_Float16*)(ws + 32 * MB);
  _Float16*       act2h = (_Float16*)(ws + 64 * MB);       // 64 MB [256][64][64][32] NHWC f16
  _Float16*       act2l = (_Float16*)(ws + 128 * MB);
  unsigned short* act3h = (unsigned short*)(ws + 192 * MB); // 128 MB [256][64][4096] NCHW bf16
  unsigned short* act3l = (unsigned short*)(ws + 320 * MB); // 128 MB bf16 lo (unscaled)
  float*    P     = (float*)(ws);                          // 64 MB [64][256][1024]
  _Float16* wp2h  = (_Float16*)(ws + 448 * MB);
  _Float16* wp2l  = (_Float16*)(ws + 448 * MB + 64 * KB);
  _Float16* wp3h  = (_Float16*)(ws + 448 * MB + 128 * KB);
  _Float16* wp3l  = (_Float16*)(ws + 448 * MB + 192 * KB);
  float*    s2    = (float*)(ws + 448 * MB + 256 * KB);
  int*      topi  = (int*)(ws + 448 * MB + 512 * KB);
  float*    topv  = (float*)(ws + 448 * MB + 516 * KB);
  float*    s1    = (float*)(ws + 449 * MB);               // 1 MB
  float*    out   = (float*)d_out;

  prepack_w<<<(32 * 192 + 255) / 256, 256, 0, stream>>>(conv2_w, wp2h, wp2l, 32, 16, 64);
  prepack_w<<<(64 * 288 + 255) / 256, 256, 0, stream>>>(conv3_w, wp3h, wp3l, 64, 32, 96);

  conv1_k<<<dim3(16, 256), 256, 0, stream>>>(obs, conv1_w, conv1_b, act1h, act1l);
  conv_mfma<16, 32, false><<<dim3(32, 256), 256, 0, stream>>>(act1h, act1l, wp2h, wp2l, conv2_b,
                                                              (unsigned short*)act2h, (unsigned short*)act2l);
  conv_mfma<32, 64, true ><<<dim3(32, 256), 256, 0, stream>>>(act2h, act2l, wp3h, wp3l, conv3_b,
                                                              act3h, act3l);

  fc1_gemm_v13<<<dim3(64, 4), 512, 0, stream>>>(act3h, act3l, fc1_w, P);
  fc1_reduce<<<1024, 256, 0, stream>>>(P, fc1_b, s1);
  fc2_k<<<256, 256, 0, stream>>>(s1, fc2_w, fc2_b, s2);
  gate_k<<<256, 64, 0, stream>>>(s2, gate_w, gate_b, out + 256 * 18, topi, topv);
  expert_k<<<256, 256, 0, stream>>>(s2, exp_w1, exp_b1, exp_w2, exp_b2, topi, topv, out);
}

// Round 14
// 893.823 us; speedup vs baseline: 1.6952x; 1.6952x over previous
//
#include <hip/hip_runtime.h>

typedef _Float16 f16x8 __attribute__((ext_vector_type(8)));
typedef short    s16x8 __attribute__((ext_vector_type(8)));
typedef float    f32x4 __attribute__((ext_vector_type(4)));

__device__ __forceinline__ unsigned short f2bf(float f) {
  union { float f; unsigned u; } x; x.f = f;
  unsigned r = (x.u + 0x7fffu + ((x.u >> 16) & 1u)) >> 16;  // RNE
  return (unsigned short)r;
}
__device__ __forceinline__ float bf2f(unsigned short u) {
  union { unsigned u; float f; } x; x.u = ((unsigned)u) << 16; return x.f;
}

// ================= weight prepack: OIHW fp32 -> [oc][3*KPAD] split hi/lo f16 =================
__global__ void prepack_w(const float* __restrict__ w, _Float16* __restrict__ ph,
                          _Float16* __restrict__ pl, int COUT, int CIN, int KPAD)
{
  const int idx = blockIdx.x * 256 + threadIdx.x;
  const int KTOT = 3 * KPAD;
  if (idx >= COUT * KTOT) return;
  const int oc = idx / KTOT;
  const int rem = idx - oc * KTOT;
  const int y = rem / KPAD;
  const int kk = rem - y * KPAD;
  float v = 0.f;
  if (kk < 3 * CIN) {
    const int tx = kk / CIN;
    const int ic = kk - tx * CIN;
    v = w[((size_t)oc * CIN + ic) * 9 + y * 3 + tx];
  }
  const _Float16 h = (_Float16)v;
  ph[idx] = h;
  pl[idx] = (_Float16)((v - (float)h) * 2048.0f);
}

// ================= conv1: CIN=1, VALU fp32, NHWC split-f16 out =================
__global__ __launch_bounds__(256)
void conv1_k(const float* __restrict__ obs, const float* __restrict__ w,
             const float* __restrict__ bias, _Float16* __restrict__ outh,
             _Float16* __restrict__ outl)
{
  const int rg = blockIdx.x;
  const int b = blockIdx.y;
  const int tid = threadIdx.x;
  const int lr = tid >> 6;
  const int col = tid & 63;
  __shared__ float xs[6][66];
  __shared__ float wb[9][16];
  for (int idx = tid; idx < 6 * 66; idx += 256) {
    const int r = idx / 66, c = idx - (idx / 66) * 66;
    const int gr = rg * 4 - 1 + r, gc = c - 1;
    xs[r][c] = (gr >= 0 && gr < 64 && gc >= 0 && gc < 64)
                   ? obs[(size_t)b * 4096 + gr * 64 + gc] : 0.f;
  }
  if (tid < 144) wb[tid / 16][tid & 15] = w[(tid & 15) * 9 + tid / 16];
  __syncthreads();
  float acc[16];
#pragma unroll
  for (int o = 0; o < 16; ++o) acc[o] = bias[o];
#pragma unroll
  for (int ty = 0; ty < 3; ++ty)
#pragma unroll
    for (int tx = 0; tx < 3; ++tx) {
      const float x = xs[lr + ty][col + tx];
#pragma unroll
      for (int o = 0; o < 16; ++o) acc[o] = fmaf(x, wb[ty * 3 + tx][o], acc[o]);
    }
  const size_t base = ((size_t)(b * 64 + rg * 4 + lr) * 64 + col) * 16;
#pragma unroll
  for (int o = 0; o < 16; ++o) {
    const float v = fmaxf(acc[o], 0.f);
    const _Float16 h = (_Float16)v;
    outh[base + o] = h;
    outl[base + o] = (_Float16)((v - (float)h) * 2048.0f);
  }
}

// ================= conv MFMA: NHWC shift-GEMM, split-f16 3-term =================
// NCHW_OUT: epilogue transposes via LDS, stores bf16 hi + bf16 lo (unscaled) for fc1
template<int CIN, int COUT, bool NCHW_OUT>
__global__ __launch_bounds__(256)
void conv_mfma(const _Float16* __restrict__ inh, const _Float16* __restrict__ inl,
               const _Float16* __restrict__ wph, const _Float16* __restrict__ wpl,
               const float* __restrict__ bias,
               unsigned short* __restrict__ outh, unsigned short* __restrict__ outl)
{
  constexpr int KFX = (3 * CIN + 31) / 32;
  constexpr int KPAD = KFX * 32;
  constexpr int KTOT = 3 * KPAD;
  constexpr int CP = CIN + 8;
  constexpr int NF = COUT / 32;
  constexpr int STO = NCHW_OUT ? COUT : 1;
  constexpr int STP = NCHW_OUT ? 136 : 8;
  const int rp = blockIdx.x;
  const int b  = blockIdx.y;
  const int r0 = rp * 2;
  const int tid = threadIdx.x;
  const int lane = tid & 63;
  const int wid = tid >> 6;
  const int wm = wid >> 1;
  const int wn = wid & 1;

  __shared__ _Float16 xh[4][68][CP];
  __shared__ _Float16 xl[4][68][CP];
  __shared__ unsigned short st_h[STO][STP];
  __shared__ unsigned short st_l[STO][STP];

  constexpr int CH = CIN / 8;
  for (int idx = tid; idx < 4 * 68 * CH; idx += 256) {
    const int r = idx / (68 * CH);
    const int rem = idx - r * 68 * CH;
    const int hc = rem / CH;
    const int ch = rem - hc * CH;
    const int gr = r0 - 1 + r;
    const int gc = hc - 1;
    uint4 vh = {0, 0, 0, 0}, vl = {0, 0, 0, 0};
    if (gr >= 0 && gr < 64 && gc >= 0 && gc < 64) {
      const size_t base = ((size_t)(b * 64 + gr) * 64 + gc) * CIN + ch * 8;
      vh = *(const uint4*)(inh + base);
      vl = *(const uint4*)(inl + base);
    }
    *(uint4*)&xh[r][hc][ch * 8] = vh;
    *(uint4*)&xl[r][hc][ch * 8] = vl;
  }
  __syncthreads();

  f32x4 accm[4][NF];
  f32x4 accc[4][NF];
#pragma unroll
  for (int mf = 0; mf < 4; ++mf)
#pragma unroll
    for (int nf = 0; nf < NF; ++nf) { accm[mf][nf] = {}; accc[mf][nf] = {}; }

  const int lm = lane & 15;
  const int ch8 = (lane >> 4) * 8;

#pragma unroll
  for (int kf = 0; kf < 3 * KFX; ++kf) {
    const int y = kf / KFX;
    const int fx = kf - y * KFX;
    const int kk = fx * 32 + ch8;
    f16x8 bh[NF], bl[NF];
#pragma unroll
    for (int nf = 0; nf < NF; ++nf) {
      const int oc = wn * (16 * NF) + nf * 16 + lm;
      bh[nf] = *(const f16x8*)(wph + (size_t)oc * KTOT + kf * 32 + ch8);
      bl[nf] = *(const f16x8*)(wpl + (size_t)oc * KTOT + kf * 32 + ch8);
    }
#pragma unroll
    for (int mf = 0; mf < 4; ++mf) {
      const int col = mf * 16 + lm;
      const f16x8 ah = *(const f16x8*)&xh[wm + y][col + kk / CIN][kk % CIN];
      const f16x8 al = *(const f16x8*)&xl[wm + y][col + kk / CIN][kk % CIN];
#pragma unroll
      for (int nf = 0; nf < NF; ++nf) {
        accm[mf][nf] = __builtin_amdgcn_mfma_f32_16x16x32_f16(ah, bh[nf], accm[mf][nf], 0, 0, 0);
        accc[mf][nf] = __builtin_amdgcn_mfma_f32_16x16x32_f16(ah, bl[nf], accc[mf][nf], 0, 0, 0);
        accc[mf][nf] = __builtin_amdgcn_mfma_f32_16x16x32_f16(al, bh[nf], accc[mf][nf], 0, 0, 0);
      }
    }
  }

  if constexpr (NCHW_OUT) {
    // ---- stage bf16(hi) + bf16(lo, unscaled) to LDS, then contiguous NCHW stores ----
#pragma unroll
    for (int nf = 0; nf < NF; ++nf) {
      const int oc = wn * (16 * NF) + nf * 16 + lm;
      const float bv = bias[oc];
#pragma unroll
      for (int mf = 0; mf < 4; ++mf) {
        unsigned short hv[4], lv[4];
#pragma unroll
        for (int r = 0; r < 4; ++r) {
          const float v = fmaxf(accm[mf][nf][r] + accc[mf][nf][r] * (1.0f / 2048.0f) + bv, 0.f);
          const unsigned short hb = f2bf(v);
          hv[r] = hb;
          lv[r] = f2bf(v - bf2f(hb));
        }
        const int px = wm * 64 + mf * 16 + (lane >> 4) * 4;
        *(ushort4*)&st_h[oc][px] = make_ushort4(hv[0], hv[1], hv[2], hv[3]);
        *(ushort4*)&st_l[oc][px] = make_ushort4(lv[0], lv[1], lv[2], lv[3]);
      }
    }
    __syncthreads();
    const int oc2 = tid >> 2;
    const int seg = tid & 3;
    const size_t gb = ((size_t)b * COUT + oc2) * 4096 + r0 * 64 + seg * 32;
#pragma unroll
    for (int j2 = 0; j2 < 4; ++j2) {
      *(uint4*)(outh + gb + j2 * 8) = *(const uint4*)&st_h[oc2][seg * 32 + j2 * 8];
      *(uint4*)(outl + gb + j2 * 8) = *(const uint4*)&st_l[oc2][seg * 32 + j2 * 8];
    }
  } else {
    const int orow = r0 + wm;
#pragma unroll
    for (int nf = 0; nf < NF; ++nf) {
      const int oc = wn * (16 * NF) + nf * 16 + lm;
      const float bv = bias[oc];
#pragma unroll
      for (int mf = 0; mf < 4; ++mf) {
#pragma unroll
        for (int r = 0; r < 4; ++r) {
          const int x = mf * 16 + (lane >> 4) * 4 + r;
          const float v = fmaxf(accm[mf][nf][r] + accc[mf][nf][r] * (1.0f / 2048.0f) + bv, 0.f);
          const _Float16 h = (_Float16)v;
          union { _Float16 f; unsigned short u; } ch_, cl_;
          ch_.f = h;
          cl_.f = (_Float16)((v - (float)h) * 2048.0f);
          const size_t oi = ((size_t)(b * 64 + orow) * 64 + x) * COUT + oc;
          outh[oi] = ch_.u;
          outl[oi] = cl_.u;
        }
      }
    }
  }
}

// ================= fc1 v14 (= v11 revert): bf16 hi/lo, single acc, BN=256, v4 pipeline =================
// grid(64 sk, 4 nt) = 256 blocks (1/CU). block 512 = 8 waves (4M x 2N), wave 64x128.
// K-slice 4096, BK=32, 128 its. LDS 128 KB.
__global__ __launch_bounds__(512, 2)
void fc1_gemm_v14(const unsigned short* __restrict__ Ahi, const unsigned short* __restrict__ Alo,
                  const float* __restrict__ W, float* __restrict__ P)
{
  const int sk = blockIdx.x;
  const int nt = blockIdx.y;
  const int nc0 = nt * 256;
  const int tid = threadIdx.x;
  const int lane = tid & 63;
  const int wid = tid >> 6;
  const int wm = wid >> 1;          // 0..3
  const int wn = wid & 1;           // 0..1

  __shared__ unsigned short Ah[2][256][32];   // 32 KB
  __shared__ unsigned short Al[2][256][32];   // 32 KB
  __shared__ unsigned short Bh[2][256][32];   // 32 KB
  __shared__ unsigned short Bl[2][256][32];   // 32 KB

  f32x4 acc[4][8] = {};

  const int nl = tid & 255;         // B col 0..255
  const int kq = tid >> 8;          // 0..1 -> k rows kq*16..+16
  const int q = lane >> 4;          // fragment k-slot

  const size_t kbase = (size_t)sk * 4096;
  constexpr int NIT = 128;

  // ---- A DMA mapping (v4-verbatim): wave wid stages rows wid*32..+32 ----
  const int Rbase = wid * 32;
  const int lrow0 = Rbase + (lane >> 2);
  const int lrow1 = Rbase + 16 + (lane >> 2);
  const int sd = lane & 3;
  const int ssrc0 = sd ^ ((lrow0 >> 1) & 3);
  const int ssrc1 = sd ^ ((lrow1 >> 1) & 3);
  const size_t goff0 = (size_t)lrow0 * 262144 + ssrc0 * 8;
  const size_t goff1 = (size_t)lrow1 * 262144 + ssrc1 * 8;

#define ISSUE_A(p, k0)                                                                     \
  {                                                                                        \
    __builtin_amdgcn_global_load_lds(                                                      \
        (const __attribute__((address_space(1))) unsigned int*)(Ahi + goff0 + (k0)),       \
        (__attribute__((address_space(3))) unsigned int*)&Ah[p][Rbase][0], 16, 0, 0);      \
    __builtin_amdgcn_global_load_lds(                                                      \
        (const __attribute__((address_space(1))) unsigned int*)(Ahi + goff1 + (k0)),       \
        (__attribute__((address_space(3))) unsigned int*)&Ah[p][Rbase + 16][0], 16, 0, 0); \
    __builtin_amdgcn_global_load_lds(                                                      \
        (const __attribute__((address_space(1))) unsigned int*)(Alo + goff0 + (k0)),       \
        (__attribute__((address_space(3))) unsigned int*)&Al[p][Rbase][0], 16, 0, 0);      \
    __builtin_amdgcn_global_load_lds(                                                      \
        (const __attribute__((address_space(1))) unsigned int*)(Alo + goff1 + (k0)),       \
        (__attribute__((address_space(3))) unsigned int*)&Al[p][Rbase + 16][0], 16, 0, 0); \
  }

#define LOAD_W(k0, wr)                                                      \
  {                                                                         \
    const float* wp_ = W + ((k0) + kq * 16) * 1024 + nc0 + nl;              \
    _Pragma("unroll") for (int i = 0; i < 16; ++i) {                        \
      wr[i] = wp_[(size_t)i * 1024];                                        \
    }                                                                       \
  }

#define WRITE_B(p, wr)                                                      \
  {                                                                         \
    _Pragma("unroll") for (int h2 = 0; h2 < 2; ++h2) {                      \
      s16x8 hv, lv;                                                         \
      _Pragma("unroll") for (int j = 0; j < 8; ++j) {                       \
        const float f = wr[h2 * 8 + j];                                     \
        const unsigned short hb = f2bf(f);                                  \
        hv[j] = (short)hb;                                                  \
        lv[j] = (short)f2bf(f - bf2f(hb));                                  \
      }                                                                     \
      const int sw = (kq * 2 + h2) ^ ((nl >> 1) & 3);                       \
      *(s16x8*)&Bh[p][nl][sw * 8] = hv;                                     \
      *(s16x8*)&Bl[p][nl][sw * 8] = lv;                                     \
    }                                                                       \
  }

#define COMPUTE(p)                                                                          \
  {                                                                                         \
    s16x8 ah[4], al[4];                                                                     \
    _Pragma("unroll") for (int mf = 0; mf < 4; ++mf) {                                      \
      const int r = wm * 64 + mf * 16 + (lane & 15);                                        \
      const int s = (q ^ ((r >> 1) & 3)) * 8;                                               \
      ah[mf] = *(const s16x8*)&Ah[p][r][s];                                                 \
      al[mf] = *(const s16x8*)&Al[p][r][s];                                                 \
    }                                                                                       \
    _Pragma("unroll") for (int hf = 0; hf < 2; ++hf) {                                      \
      s16x8 bh[4], bl[4];                                                                   \
      _Pragma("unroll") for (int nf = 0; nf < 4; ++nf) {                                    \
        const int n = wn * 128 + (hf * 4 + nf) * 16 + (lane & 15);                          \
        const int s = (q ^ ((n >> 1) & 3)) * 8;                                             \
        bh[nf] = *(const s16x8*)&Bh[p][n][s];                                               \
        bl[nf] = *(const s16x8*)&Bl[p][n][s];                                               \
      }                                                                                     \
      __builtin_amdgcn_s_setprio(1);                                                        \
      _Pragma("unroll") for (int mf = 0; mf < 4; ++mf)                                      \
        _Pragma("unroll") for (int nf = 0; nf < 4; ++nf) {                                  \
          acc[mf][hf*4+nf] = __builtin_amdgcn_mfma_f32_16x16x32_bf16(ah[mf], bh[nf], acc[mf][hf*4+nf], 0, 0, 0); \
          acc[mf][hf*4+nf] = __builtin_amdgcn_mfma_f32_16x16x32_bf16(al[mf], bh[nf], acc[mf][hf*4+nf], 0, 0, 0); \
          acc[mf][hf*4+nf] = __builtin_amdgcn_mfma_f32_16x16x32_bf16(ah[mf], bl[nf], acc[mf][hf*4+nf], 0, 0, 0); \
        }                                                                                   \
      __builtin_amdgcn_s_setprio(0);                                                        \
    }                                                                                       \
  }

  // ---- prologue (v4 scheme): tile-1 loads stay in flight across the barrier ----
  {
    float wr[16];
    LOAD_W(kbase, wr);             // W(0): 16 loads
    ISSUE_A(0, kbase);             // DMA(0): 4 ops
    WRITE_B(0, wr);                // waits W(0) only; DMA(0) outstanding
    LOAD_W(kbase + 32, wr);        // W(1): 16 loads
    ISSUE_A(1, kbase + 32);        // DMA(1): 4 ops
    // outstanding: DMA(0)=4 (oldest, must finish) + W(1)=16 + DMA(1)=4 -> keep 20 newest
    asm volatile("s_waitcnt vmcnt(20)\n\ts_waitcnt lgkmcnt(0)\n\ts_barrier" ::: "memory");
  }

  {
    float wr[16];
    LOAD_W(kbase + 32, wr);        // W(1) into live regs (prologue-only L2 re-read)
    for (int it = 0; it < NIT - 1; ++it) {
      const int cur = it & 1;
      COMPUTE(cur);
      WRITE_B(cur ^ 1, wr);        // B(it+1); waits its own W loads only
      asm volatile("s_waitcnt vmcnt(0)\n\ts_waitcnt lgkmcnt(0)\n\ts_barrier" ::: "memory");
      if (it + 2 < NIT) {
        const size_t k2 = kbase + (size_t)(it + 2) * 32;
        LOAD_W(k2, wr);            // consumed next iteration
        ISSUE_A(cur, k2);          // into buf cur (readers done at barrier above)
      }
    }
    COMPUTE((NIT - 1) & 1);
  }
#undef ISSUE_A
#undef LOAD_W
#undef WRITE_B
#undef COMPUTE

  // epilogue: C/D layout col=lane&15, row=(lane>>4)*4+r
#pragma unroll
  for (int mf = 0; mf < 4; ++mf) {
    const int rbase = wm * 64 + mf * 16 + ((lane >> 4) << 2);
#pragma unroll
    for (int nf = 0; nf < 8; ++nf) {
      const int c = nc0 + wn * 128 + nf * 16 + (lane & 15);
#pragma unroll
      for (int r = 0; r < 4; ++r)
        P[((size_t)sk * 256 + rbase + r) * 1024 + c] = acc[mf][nf][r];
    }
  }
}

// ================= fc1 reduce (64 partials) =================
__global__ __launch_bounds__(256)
void fc1_reduce(const float* __restrict__ P, const float* __restrict__ bias,
                float* __restrict__ s1)
{
  const int idx = blockIdx.x * 256 + threadIdx.x;
  const int n = idx & 1023;
  float a = bias[n];
#pragma unroll 8
  for (int sk = 0; sk < 64; ++sk) a += P[(size_t)sk * 262144 + idx];
  s1[idx] = fmaxf(a, 0.f);
}

// ================= fc2 =================
__global__ __launch_bounds__(256)
void fc2_k(const float* __restrict__ s1, const float* __restrict__ w,
           const float* __restrict__ b, float* __restrict__ s2)
{
  const int bb = blockIdx.x;
  const int t = threadIdx.x;
  __shared__ float xr[1024];
  for (int i = t; i < 1024; i += 256) xr[i] = s1[bb * 1024 + i];
  __syncthreads();
  float a0 = b[t], a1 = 0.f, a2 = 0.f, a3 = 0.f;
#pragma unroll 4
  for (int k = 0; k < 1024; k += 4) {
    a0 += xr[k + 0] * w[(k + 0) * 256 + t];
    a1 += xr[k + 1] * w[(k + 1) * 256 + t];
    a2 += xr[k + 2] * w[(k + 2) * 256 + t];
    a3 += xr[k + 3] * w[(k + 3) * 256 + t];
  }
  s2[bb * 256 + t] = fmaxf(a0 + a1 + a2 + a3, 0.f);
}

// ================= gate =================
__global__ __launch_bounds__(64)
void gate_k(const float* __restrict__ s2, const float* __restrict__ gw,
            const float* __restrict__ gb, float* __restrict__ gate_out,
            int* __restrict__ topi, float* __restrict__ topv)
{
  const int bb = blockIdx.x;
  const int l = threadIdx.x;
  float part[8] = {};
  for (int k = l; k < 256; k += 64) {
    const float x = s2[bb * 256 + k];
#pragma unroll
    for (int e = 0; e < 8; ++e) part[e] += x * gw[k * 8 + e];
  }
#pragma unroll
  for (int off = 32; off > 0; off >>= 1)
#pragma unroll
    for (int e = 0; e < 8; ++e) part[e] += __shfl_down(part[e], off);

  if (l == 0) {
    float lg[8];
    float m = -1e30f;
#pragma unroll
    for (int e = 0; e < 8; ++e) { lg[e] = part[e] + gb[e]; m = fmaxf(m, lg[e]); }
    float s = 0.f;
    float p[8];
#pragma unroll
    for (int e = 0; e < 8; ++e) { p[e] = expf(lg[e] - m); s += p[e]; }
#pragma unroll
    for (int e = 0; e < 8; ++e) { p[e] = p[e] / s; gate_out[bb * 8 + e] = p[e]; }
    int i0 = 0;
#pragma unroll
    for (int e = 1; e < 8; ++e) if (p[e] > p[i0]) i0 = e;
    int i1 = (i0 == 0) ? 1 : 0;
#pragma unroll
    for (int e = 0; e < 8; ++e) if (e != i0 && p[e] > p[i1]) i1 = e;
    const float v0 = p[i0], v1 = p[i1];
    topi[bb * 2 + 0] = i0; topi[bb * 2 + 1] = i1;
    topv[bb * 2 + 0] = v0 / (v0 + v1); topv[bb * 2 + 1] = v1 / (v0 + v1);
  }
}

// ================= experts =================
__global__ __launch_bounds__(256)
void expert_k(const float* __restrict__ s2, const float* __restrict__ w1,
              const float* __restrict__ b1, const float* __restrict__ w2,
              const float* __restrict__ b2, const int* __restrict__ topi,
              const float* __restrict__ topv, float* __restrict__ out)
{
  const int bb = blockIdx.x;
  const int t = threadIdx.x;
  __shared__ float xr[256];
  __shared__ float eh[512];
  __shared__ float partial[18][8];
  xr[t] = s2[bb * 256 + t];
  float logit = 0.f;
  for (int kk = 0; kk < 2; ++kk) {
    __syncthreads();
    const int e = topi[bb * 2 + kk];
    const float tv = topv[bb * 2 + kk];
    const float* W1 = w1 + (size_t)e * 256 * 512;
    float a0 = b1[e * 512 + t], a1 = b1[e * 512 + 256 + t];
#pragma unroll 4
    for (int k = 0; k < 256; ++k) {
      const float x = xr[k];
      a0 = fmaf(x, W1[k * 512 + t], a0);
      a1 = fmaf(x, W1[k * 512 + 256 + t], a1);
    }
    eh[t] = fmaxf(a0, 0.f);
    eh[256 + t] = fmaxf(a1, 0.f);
    __syncthreads();
    if (t < 144) {
      const int a = t >> 3, q2 = t & 7;
      const float* W2 = w2 + (size_t)e * 512 * 18;
      float pp = 0.f;
      for (int h = q2 * 64; h < q2 * 64 + 64; ++h) pp = fmaf(eh[h], W2[h * 18 + a], pp);
      partial[a][q2] = pp;
    }
    __syncthreads();
    if (t < 18) {
      float s = b2[e * 18 + t];
#pragma unroll
      for (int q2 = 0; q2 < 8; ++q2) s += partial[t][q2];
      logit = fmaf(tv, s, logit);
    }
  }
  if (t < 18) out[bb * 18 + t] = logit;
}

// ================= launch =================
extern "C" void kernel_launch(void* const* d_in, const int* in_sizes, int n_in,
                              void* d_out, int out_size, void* d_ws, size_t ws_size,
                              hipStream_t stream) {
  const float* obs     = (const float*)d_in[0];
  const float* conv1_w = (const float*)d_in[1];
  const float* conv1_b = (const float*)d_in[2];
  const float* conv2_w = (const float*)d_in[3];
  const float* conv2_b = (const float*)d_in[4];
  const float* conv3_w = (const float*)d_in[5];
  const float* conv3_b = (const float*)d_in[6];
  const float* fc1_w   = (const float*)d_in[7];
  const float* fc1_b   = (const float*)d_in[8];
  const float* fc2_w   = (const float*)d_in[9];
  const float* fc2_b   = (const float*)d_in[10];
  const float* gate_w  = (const float*)d_in[11];
  const float* gate_b  = (const float*)d_in[12];
  const float* exp_w1  = (const float*)d_in[13];
  const float* exp_b1  = (const float*)d_in[14];
  const float* exp_w2  = (const float*)d_in[15];
  const float* exp_b2  = (const float*)d_in[16];

  char* ws = (char*)d_ws;
  const size_t MB = 1ull << 20;
  const size_t KB = 1ull << 10;
  _Float16*       act1h = (_Float16*)(ws);                 // 32 MB [256][64][64][16] NHWC f16
  _Float16*       act1l = (_Float16*)(ws + 32 * MB);
  _Float16*       act2h = (_Float16*)(ws + 64 * MB);       // 64 MB [256][64][64][32] NHWC f16
  _Float16*       act2l = (_Float16*)(ws + 128 * MB);
  unsigned short* act3h = (unsigned short*)(ws + 192 * MB); // 128 MB [256][64][4096] NCHW bf16
  unsigned short* act3l = (unsigned short*)(ws + 320 * MB); // 128 MB bf16 lo (unscaled)
  float*    P     = (float*)(ws);                          // 64 MB [64][256][1024]
  _Float16* wp2h  = (_Float16*)(ws + 448 * MB);
  _Float16* wp2l  = (_Float16*)(ws + 448 * MB + 64 * KB);
  _Float16* wp3h  = (_Float16*)(ws + 448 * MB + 128 * KB);
  _Float16* wp3l  = (_Float16*)(ws + 448 * MB + 192 * KB);
  float*    s2    = (float*)(ws + 448 * MB + 256 * KB);
  int*      topi  = (int*)(ws + 448 * MB + 512 * KB);
  float*    topv  = (float*)(ws + 448 * MB + 516 * KB);
  float*    s1    = (float*)(ws + 449 * MB);               // 1 MB
  float*    out   = (float*)d_out;

  prepack_w<<<(32 * 192 + 255) / 256, 256, 0, stream>>>(conv2_w, wp2h, wp2l, 32, 16, 64);
  prepack_w<<<(64 * 288 + 255) / 256, 256, 0, stream>>>(conv3_w, wp3h, wp3l, 64, 32, 96);

  conv1_k<<<dim3(16, 256), 256, 0, stream>>>(obs, conv1_w, conv1_b, act1h, act1l);
  conv_mfma<16, 32, false><<<dim3(32, 256), 256, 0, stream>>>(act1h, act1l, wp2h, wp2l, conv2_b,
                                                              (unsigned short*)act2h, (unsigned short*)act2l);
  conv_mfma<32, 64, true ><<<dim3(32, 256), 256, 0, stream>>>(act2h, act2l, wp3h, wp3l, conv3_b,
                                                              act3h, act3l);

  fc1_gemm_v14<<<dim3(64, 4), 512, 0, stream>>>(act3h, act3l, fc1_w, P);
  fc1_reduce<<<1024, 256, 0, stream>>>(P, fc1_b, s1);
  fc2_k<<<256, 256, 0, stream>>>(s1, fc2_w, fc2_b, s2);
  gate_k<<<256, 64, 0, stream>>>(s2, gate_w, gate_b, out + 256 * 18, topi, topv);
  expert_k<<<256, 256, 0, stream>>>(s2, exp_w1, exp_b1, exp_w2, exp_b2, topi, topv, out);
}

// Round 15
// 893.541 us; speedup vs baseline: 1.6957x; 1.0003x over previous
//
#include <hip/hip_runtime.h>

typedef _Float16 f16x8 __attribute__((ext_vector_type(8)));
typedef short    s16x8 __attribute__((ext_vector_type(8)));
typedef float    f32x4 __attribute__((ext_vector_type(4)));

__device__ __forceinline__ unsigned short f2bf(float f) {
  union { float f; unsigned u; } x; x.f = f;
  unsigned r = (x.u + 0x7fffu + ((x.u >> 16) & 1u)) >> 16;  // RNE
  return (unsigned short)r;
}
__device__ __forceinline__ float bf2f(unsigned short u) {
  union { unsigned u; float f; } x; x.u = ((unsigned)u) << 16; return x.f;
}

// ================= weight prepack: OIHW fp32 -> [oc][3*KPAD] split hi/lo f16 =================
__global__ void prepack_w(const float* __restrict__ w, _Float16* __restrict__ ph,
                          _Float16* __restrict__ pl, int COUT, int CIN, int KPAD)
{
  const int idx = blockIdx.x * 256 + threadIdx.x;
  const int KTOT = 3 * KPAD;
  if (idx >= COUT * KTOT) return;
  const int oc = idx / KTOT;
  const int rem = idx - oc * KTOT;
  const int y = rem / KPAD;
  const int kk = rem - y * KPAD;
  float v = 0.f;
  if (kk < 3 * CIN) {
    const int tx = kk / CIN;
    const int ic = kk - tx * CIN;
    v = w[((size_t)oc * CIN + ic) * 9 + y * 3 + tx];
  }
  const _Float16 h = (_Float16)v;
  ph[idx] = h;
  pl[idx] = (_Float16)((v - (float)h) * 2048.0f);
}

// ================= conv1: CIN=1, VALU fp32, NHWC split-f16 out =================
__global__ __launch_bounds__(256)
void conv1_k(const float* __restrict__ obs, const float* __restrict__ w,
             const float* __restrict__ bias, _Float16* __restrict__ outh,
             _Float16* __restrict__ outl)
{
  const int rg = blockIdx.x;
  const int b = blockIdx.y;
  const int tid = threadIdx.x;
  const int lr = tid >> 6;
  const int col = tid & 63;
  __shared__ float xs[6][66];
  __shared__ float wb[9][16];
  for (int idx = tid; idx < 6 * 66; idx += 256) {
    const int r = idx / 66, c = idx - (idx / 66) * 66;
    const int gr = rg * 4 - 1 + r, gc = c - 1;
    xs[r][c] = (gr >= 0 && gr < 64 && gc >= 0 && gc < 64)
                   ? obs[(size_t)b * 4096 + gr * 64 + gc] : 0.f;
  }
  if (tid < 144) wb[tid / 16][tid & 15] = w[(tid & 15) * 9 + tid / 16];
  __syncthreads();
  float acc[16];
#pragma unroll
  for (int o = 0; o < 16; ++o) acc[o] = bias[o];
#pragma unroll
  for (int ty = 0; ty < 3; ++ty)
#pragma unroll
    for (int tx = 0; tx < 3; ++tx) {
      const float x = xs[lr + ty][col + tx];
#pragma unroll
      for (int o = 0; o < 16; ++o) acc[o] = fmaf(x, wb[ty * 3 + tx][o], acc[o]);
    }
  const size_t base = ((size_t)(b * 64 + rg * 4 + lr) * 64 + col) * 16;
#pragma unroll
  for (int o = 0; o < 16; ++o) {
    const float v = fmaxf(acc[o], 0.f);
    const _Float16 h = (_Float16)v;
    outh[base + o] = h;
    outl[base + o] = (_Float16)((v - (float)h) * 2048.0f);
  }
}

// ================= conv MFMA: NHWC shift-GEMM, split-f16 3-term =================
// NCHW_OUT: epilogue transposes via LDS, stores bf16 hi + bf16 lo (unscaled) for fc1
template<int CIN, int COUT, bool NCHW_OUT>
__global__ __launch_bounds__(256)
void conv_mfma(const _Float16* __restrict__ inh, const _Float16* __restrict__ inl,
               const _Float16* __restrict__ wph, const _Float16* __restrict__ wpl,
               const float* __restrict__ bias,
               unsigned short* __restrict__ outh, unsigned short* __restrict__ outl)
{
  constexpr int KFX = (3 * CIN + 31) / 32;
  constexpr int KPAD = KFX * 32;
  constexpr int KTOT = 3 * KPAD;
  constexpr int CP = CIN + 8;
  constexpr int NF = COUT / 32;
  constexpr int STO = NCHW_OUT ? COUT : 1;
  constexpr int STP = NCHW_OUT ? 136 : 8;
  const int rp = blockIdx.x;
  const int b  = blockIdx.y;
  const int r0 = rp * 2;
  const int tid = threadIdx.x;
  const int lane = tid & 63;
  const int wid = tid >> 6;
  const int wm = wid >> 1;
  const int wn = wid & 1;

  __shared__ _Float16 xh[4][68][CP];
  __shared__ _Float16 xl[4][68][CP];
  __shared__ unsigned short st_h[STO][STP];
  __shared__ unsigned short st_l[STO][STP];

  constexpr int CH = CIN / 8;
  for (int idx = tid; idx < 4 * 68 * CH; idx += 256) {
    const int r = idx / (68 * CH);
    const int rem = idx - r * 68 * CH;
    const int hc = rem / CH;
    const int ch = rem - hc * CH;
    const int gr = r0 - 1 + r;
    const int gc = hc - 1;
    uint4 vh = {0, 0, 0, 0}, vl = {0, 0, 0, 0};
    if (gr >= 0 && gr < 64 && gc >= 0 && gc < 64) {
      const size_t base = ((size_t)(b * 64 + gr) * 64 + gc) * CIN + ch * 8;
      vh = *(const uint4*)(inh + base);
      vl = *(const uint4*)(inl + base);
    }
    *(uint4*)&xh[r][hc][ch * 8] = vh;
    *(uint4*)&xl[r][hc][ch * 8] = vl;
  }
  __syncthreads();

  f32x4 accm[4][NF];
  f32x4 accc[4][NF];
#pragma unroll
  for (int mf = 0; mf < 4; ++mf)
#pragma unroll
    for (int nf = 0; nf < NF; ++nf) { accm[mf][nf] = {}; accc[mf][nf] = {}; }

  const int lm = lane & 15;
  const int ch8 = (lane >> 4) * 8;

#pragma unroll
  for (int kf = 0; kf < 3 * KFX; ++kf) {
    const int y = kf / KFX;
    const int fx = kf - y * KFX;
    const int kk = fx * 32 + ch8;
    f16x8 bh[NF], bl[NF];
#pragma unroll
    for (int nf = 0; nf < NF; ++nf) {
      const int oc = wn * (16 * NF) + nf * 16 + lm;
      bh[nf] = *(const f16x8*)(wph + (size_t)oc * KTOT + kf * 32 + ch8);
      bl[nf] = *(const f16x8*)(wpl + (size_t)oc * KTOT + kf * 32 + ch8);
    }
#pragma unroll
    for (int mf = 0; mf < 4; ++mf) {
      const int col = mf * 16 + lm;
      const f16x8 ah = *(const f16x8*)&xh[wm + y][col + kk / CIN][kk % CIN];
      const f16x8 al = *(const f16x8*)&xl[wm + y][col + kk / CIN][kk % CIN];
#pragma unroll
      for (int nf = 0; nf < NF; ++nf) {
        accm[mf][nf] = __builtin_amdgcn_mfma_f32_16x16x32_f16(ah, bh[nf], accm[mf][nf], 0, 0, 0);
        accc[mf][nf] = __builtin_amdgcn_mfma_f32_16x16x32_f16(ah, bl[nf], accc[mf][nf], 0, 0, 0);
        accc[mf][nf] = __builtin_amdgcn_mfma_f32_16x16x32_f16(al, bh[nf], accc[mf][nf], 0, 0, 0);
      }
    }
  }

  if constexpr (NCHW_OUT) {
#pragma unroll
    for (int nf = 0; nf < NF; ++nf) {
      const int oc = wn * (16 * NF) + nf * 16 + lm;
      const float bv = bias[oc];
#pragma unroll
      for (int mf = 0; mf < 4; ++mf) {
        unsigned short hv[4], lv[4];
#pragma unroll
        for (int r = 0; r < 4; ++r) {
          const float v = fmaxf(accm[mf][nf][r] + accc[mf][nf][r] * (1.0f / 2048.0f) + bv, 0.f);
          const unsigned short hb = f2bf(v);
          hv[r] = hb;
          lv[r] = f2bf(v - bf2f(hb));
        }
        const int px = wm * 64 + mf * 16 + (lane >> 4) * 4;
        *(ushort4*)&st_h[oc][px] = make_ushort4(hv[0], hv[1], hv[2], hv[3]);
        *(ushort4*)&st_l[oc][px] = make_ushort4(lv[0], lv[1], lv[2], lv[3]);
      }
    }
    __syncthreads();
    const int oc2 = tid >> 2;
    const int seg = tid & 3;
    const size_t gb = ((size_t)b * COUT + oc2) * 4096 + r0 * 64 + seg * 32;
#pragma unroll
    for (int j2 = 0; j2 < 4; ++j2) {
      *(uint4*)(outh + gb + j2 * 8) = *(const uint4*)&st_h[oc2][seg * 32 + j2 * 8];
      *(uint4*)(outl + gb + j2 * 8) = *(const uint4*)&st_l[oc2][seg * 32 + j2 * 8];
    }
  } else {
    const int orow = r0 + wm;
#pragma unroll
    for (int nf = 0; nf < NF; ++nf) {
      const int oc = wn * (16 * NF) + nf * 16 + lm;
      const float bv = bias[oc];
#pragma unroll
      for (int mf = 0; mf < 4; ++mf) {
#pragma unroll
        for (int r = 0; r < 4; ++r) {
          const int x = mf * 16 + (lane >> 4) * 4 + r;
          const float v = fmaxf(accm[mf][nf][r] + accc[mf][nf][r] * (1.0f / 2048.0f) + bv, 0.f);
          const _Float16 h = (_Float16)v;
          union { _Float16 f; unsigned short u; } ch_, cl_;
          ch_.f = h;
          cl_.f = (_Float16)((v - (float)h) * 2048.0f);
          const size_t oi = ((size_t)(b * 64 + orow) * 64 + x) * COUT + oc;
          outh[oi] = ch_.u;
          outl[oi] = cl_.u;
        }
      }
    }
  }
}

// ================= fc1 (v14/v11): bf16 hi/lo, single acc, BN=256, v4 pipeline =================
// grid(64 sk, 4 nt) = 256 blocks (1/CU). block 512 = 8 waves (4M x 2N), wave 64x128.
// K-slice 4096, BK=32, 128 its. LDS 128 KB.
__global__ __launch_bounds__(512, 2)
void fc1_gemm_v14(const unsigned short* __restrict__ Ahi, const unsigned short* __restrict__ Alo,
                  const float* __restrict__ W, float* __restrict__ P)
{
  const int sk = blockIdx.x;
  const int nt = blockIdx.y;
  const int nc0 = nt * 256;
  const int tid = threadIdx.x;
  const int lane = tid & 63;
  const int wid = tid >> 6;
  const int wm = wid >> 1;          // 0..3
  const int wn = wid & 1;           // 0..1

  __shared__ unsigned short Ah[2][256][32];   // 32 KB
  __shared__ unsigned short Al[2][256][32];   // 32 KB
  __shared__ unsigned short Bh[2][256][32];   // 32 KB
  __shared__ unsigned short Bl[2][256][32];   // 32 KB

  f32x4 acc[4][8] = {};

  const int nl = tid & 255;         // B col 0..255
  const int kq = tid >> 8;          // 0..1 -> k rows kq*16..+16
  const int q = lane >> 4;          // fragment k-slot

  const size_t kbase = (size_t)sk * 4096;
  constexpr int NIT = 128;

  const int Rbase = wid * 32;
  const int lrow0 = Rbase + (lane >> 2);
  const int lrow1 = Rbase + 16 + (lane >> 2);
  const int sd = lane & 3;
  const int ssrc0 = sd ^ ((lrow0 >> 1) & 3);
  const int ssrc1 = sd ^ ((lrow1 >> 1) & 3);
  const size_t goff0 = (size_t)lrow0 * 262144 + ssrc0 * 8;
  const size_t goff1 = (size_t)lrow1 * 262144 + ssrc1 * 8;

#define ISSUE_A(p, k0)                                                                     \
  {                                                                                        \
    __builtin_amdgcn_global_load_lds(                                                      \
        (const __attribute__((address_space(1))) unsigned int*)(Ahi + goff0 + (k0)),       \
        (__attribute__((address_space(3))) unsigned int*)&Ah[p][Rbase][0], 16, 0, 0);      \
    __builtin_amdgcn_global_load_lds(                                                      \
        (const __attribute__((address_space(1))) unsigned int*)(Ahi + goff1 + (k0)),       \
        (__attribute__((address_space(3))) unsigned int*)&Ah[p][Rbase + 16][0], 16, 0, 0); \
    __builtin_amdgcn_global_load_lds(                                                      \
        (const __attribute__((address_space(1))) unsigned int*)(Alo + goff0 + (k0)),       \
        (__attribute__((address_space(3))) unsigned int*)&Al[p][Rbase][0], 16, 0, 0);      \
    __builtin_amdgcn_global_load_lds(                                                      \
        (const __attribute__((address_space(1))) unsigned int*)(Alo + goff1 + (k0)),       \
        (__attribute__((address_space(3))) unsigned int*)&Al[p][Rbase + 16][0], 16, 0, 0); \
  }

#define LOAD_W(k0, wr)                                                      \
  {                                                                         \
    const float* wp_ = W + ((k0) + kq * 16) * 1024 + nc0 + nl;              \
    _Pragma("unroll") for (int i = 0; i < 16; ++i) {                        \
      wr[i] = wp_[(size_t)i * 1024];                                        \
    }                                                                       \
  }

#define WRITE_B(p, wr)                                                      \
  {                                                                         \
    _Pragma("unroll") for (int h2 = 0; h2 < 2; ++h2) {                      \
      s16x8 hv, lv;                                                         \
      _Pragma("unroll") for (int j = 0; j < 8; ++j) {                       \
        const float f = wr[h2 * 8 + j];                                     \
        const unsigned short hb = f2bf(f);                                  \
        hv[j] = (short)hb;                                                  \
        lv[j] = (short)f2bf(f - bf2f(hb));                                  \
      }                                                                     \
      const int sw = (kq * 2 + h2) ^ ((nl >> 1) & 3);                       \
      *(s16x8*)&Bh[p][nl][sw * 8] = hv;                                     \
      *(s16x8*)&Bl[p][nl][sw * 8] = lv;                                     \
    }                                                                       \
  }

#define COMPUTE(p)                                                                          \
  {                                                                                         \
    s16x8 ah[4], al[4];                                                                     \
    _Pragma("unroll") for (int mf = 0; mf < 4; ++mf) {                                      \
      const int r = wm * 64 + mf * 16 + (lane & 15);                                        \
      const int s = (q ^ ((r >> 1) & 3)) * 8;                                               \
      ah[mf] = *(const s16x8*)&Ah[p][r][s];                                                 \
      al[mf] = *(const s16x8*)&Al[p][r][s];                                                 \
    }                                                                                       \
    _Pragma("unroll") for (int hf = 0; hf < 2; ++hf) {                                      \
      s16x8 bh[4], bl[4];                                                                   \
      _Pragma("unroll") for (int nf = 0; nf < 4; ++nf) {                                    \
        const int n = wn * 128 + (hf * 4 + nf) * 16 + (lane & 15);                          \
        const int s = (q ^ ((n >> 1) & 3)) * 8;                                             \
        bh[nf] = *(const s16x8*)&Bh[p][n][s];                                               \
        bl[nf] = *(const s16x8*)&Bl[p][n][s];                                               \
      }                                                                                     \
      __builtin_amdgcn_s_setprio(1);                                                        \
      _Pragma("unroll") for (int mf = 0; mf < 4; ++mf)                                      \
        _Pragma("unroll") for (int nf = 0; nf < 4; ++nf) {                                  \
          acc[mf][hf*4+nf] = __builtin_amdgcn_mfma_f32_16x16x32_bf16(ah[mf], bh[nf], acc[mf][hf*4+nf], 0, 0, 0); \
          acc[mf][hf*4+nf] = __builtin_amdgcn_mfma_f32_16x16x32_bf16(al[mf], bh[nf], acc[mf][hf*4+nf], 0, 0, 0); \
          acc[mf][hf*4+nf] = __builtin_amdgcn_mfma_f32_16x16x32_bf16(ah[mf], bl[nf], acc[mf][hf*4+nf], 0, 0, 0); \
        }                                                                                   \
      __builtin_amdgcn_s_setprio(0);                                                        \
    }                                                                                       \
  }

  // ---- prologue (v4 scheme): tile-1 loads stay in flight across the barrier ----
  {
    float wr[16];
    LOAD_W(kbase, wr);             // W(0): 16 loads
    ISSUE_A(0, kbase);             // DMA(0): 4 ops
    WRITE_B(0, wr);                // waits W(0) only; DMA(0) outstanding
    LOAD_W(kbase + 32, wr);        // W(1): 16 loads
    ISSUE_A(1, kbase + 32);        // DMA(1): 4 ops
    asm volatile("s_waitcnt vmcnt(20)\n\ts_waitcnt lgkmcnt(0)\n\ts_barrier" ::: "memory");
  }

  {
    float wr[16];
    LOAD_W(kbase + 32, wr);        // W(1) into live regs (prologue-only L2 re-read)
    for (int it = 0; it < NIT - 1; ++it) {
      const int cur = it & 1;
      COMPUTE(cur);
      WRITE_B(cur ^ 1, wr);        // B(it+1); waits its own W loads only
      asm volatile("s_waitcnt vmcnt(0)\n\ts_waitcnt lgkmcnt(0)\n\ts_barrier" ::: "memory");
      if (it + 2 < NIT) {
        const size_t k2 = kbase + (size_t)(it + 2) * 32;
        LOAD_W(k2, wr);            // consumed next iteration
        ISSUE_A(cur, k2);          // into buf cur (readers done at barrier above)
      }
    }
    COMPUTE((NIT - 1) & 1);
  }
#undef ISSUE_A
#undef LOAD_W
#undef WRITE_B
#undef COMPUTE

  // epilogue: C/D layout col=lane&15, row=(lane>>4)*4+r
#pragma unroll
  for (int mf = 0; mf < 4; ++mf) {
    const int rbase = wm * 64 + mf * 16 + ((lane >> 4) << 2);
#pragma unroll
    for (int nf = 0; nf < 8; ++nf) {
      const int c = nc0 + wn * 128 + nf * 16 + (lane & 15);
#pragma unroll
      for (int r = 0; r < 4; ++r)
        P[((size_t)sk * 256 + rbase + r) * 1024 + c] = acc[mf][nf][r];
    }
  }
}

// ================= fused: fc1-reduce + fc2 + gate (one block per token) =================
__global__ __launch_bounds__(256)
void fc1r_fc2_gate(const float* __restrict__ P, const float* __restrict__ fc1_b,
                   const float* __restrict__ w2, const float* __restrict__ b2,
                   const float* __restrict__ gw, const float* __restrict__ gb,
                   float* __restrict__ s2, float* __restrict__ gate_out,
                   int* __restrict__ topi, float* __restrict__ topv)
{
  const int tok = blockIdx.x;
  const int t = threadIdx.x;
  __shared__ float xr[1024];
  __shared__ float xr2[256];

  // fc1 reduce (64 partials) + bias + relu -> xr
#pragma unroll
  for (int j = 0; j < 4; ++j) {
    const int n = t + j * 256;
    float a = fc1_b[n];
#pragma unroll 8
    for (int sk = 0; sk < 64; ++sk)
      a += P[((size_t)sk * 256 + tok) * 1024 + n];
    xr[n] = fmaxf(a, 0.f);
  }
  __syncthreads();

  // fc2: s2[tok][t]
  float a0 = b2[t], a1 = 0.f, a2 = 0.f, a3 = 0.f;
#pragma unroll 4
  for (int k = 0; k < 1024; k += 4) {
    a0 += xr[k + 0] * w2[(k + 0) * 256 + t];
    a1 += xr[k + 1] * w2[(k + 1) * 256 + t];
    a2 += xr[k + 2] * w2[(k + 2) * 256 + t];
    a3 += xr[k + 3] * w2[(k + 3) * 256 + t];
  }
  const float s2v = fmaxf(a0 + a1 + a2 + a3, 0.f);
  s2[tok * 256 + t] = s2v;
  xr2[t] = s2v;
  __syncthreads();

  // gate (first wave only), identical math to previous gate_k
  if (t < 64) {
    float part[8] = {};
    for (int k = t; k < 256; k += 64) {
      const float x = xr2[k];
#pragma unroll
      for (int e = 0; e < 8; ++e) part[e] += x * gw[k * 8 + e];
    }
#pragma unroll
    for (int off = 32; off > 0; off >>= 1)
#pragma unroll
      for (int e = 0; e < 8; ++e) part[e] += __shfl_down(part[e], off);

    if (t == 0) {
      float lg[8];
      float m = -1e30f;
#pragma unroll
      for (int e = 0; e < 8; ++e) { lg[e] = part[e] + gb[e]; m = fmaxf(m, lg[e]); }
      float s = 0.f;
      float p[8];
#pragma unroll
      for (int e = 0; e < 8; ++e) { p[e] = expf(lg[e] - m); s += p[e]; }
#pragma unroll
      for (int e = 0; e < 8; ++e) { p[e] = p[e] / s; gate_out[tok * 8 + e] = p[e]; }
      int i0 = 0;
#pragma unroll
      for (int e = 1; e < 8; ++e) if (p[e] > p[i0]) i0 = e;
      int i1 = (i0 == 0) ? 1 : 0;
#pragma unroll
      for (int e = 0; e < 8; ++e) if (e != i0 && p[e] > p[i1]) i1 = e;
      const float v0 = p[i0], v1 = p[i1];
      topi[tok * 2 + 0] = i0; topi[tok * 2 + 1] = i1;
      topv[tok * 2 + 0] = v0 / (v0 + v1); topv[tok * 2 + 1] = v1 / (v0 + v1);
    }
  }
}

// ================= experts =================
__global__ __launch_bounds__(256)
void expert_k(const float* __restrict__ s2, const float* __restrict__ w1,
              const float* __restrict__ b1, const float* __restrict__ w2,
              const float* __restrict__ b2, const int* __restrict__ topi,
              const float* __restrict__ topv, float* __restrict__ out)
{
  const int bb = blockIdx.x;
  const int t = threadIdx.x;
  __shared__ float xr[256];
  __shared__ float eh[512];
  __shared__ float partial[18][8];
  xr[t] = s2[bb * 256 + t];
  float logit = 0.f;
  for (int kk = 0; kk < 2; ++kk) {
    __syncthreads();
    const int e = topi[bb * 2 + kk];
    const float tv = topv[bb * 2 + kk];
    const float* W1 = w1 + (size_t)e * 256 * 512;
    float a0 = b1[e * 512 + t], a1 = b1[e * 512 + 256 + t];
#pragma unroll 4
    for (int k = 0; k < 256; ++k) {
      const float x = xr[k];
      a0 = fmaf(x, W1[k * 512 + t], a0);
      a1 = fmaf(x, W1[k * 512 + 256 + t], a1);
    }
    eh[t] = fmaxf(a0, 0.f);
    eh[256 + t] = fmaxf(a1, 0.f);
    __syncthreads();
    if (t < 144) {
      const int a = t >> 3, q2 = t & 7;
      const float* W2 = w2 + (size_t)e * 512 * 18;
      float pp = 0.f;
      for (int h = q2 * 64; h < q2 * 64 + 64; ++h) pp = fmaf(eh[h], W2[h * 18 + a], pp);
      partial[a][q2] = pp;
    }
    __syncthreads();
    if (t < 18) {
      float s = b2[e * 18 + t];
#pragma unroll
      for (int q2 = 0; q2 < 8; ++q2) s += partial[t][q2];
      logit = fmaf(tv, s, logit);
    }
  }
  if (t < 18) out[bb * 18 + t] = logit;
}

// ================= launch =================
extern "C" void kernel_launch(void* const* d_in, const int* in_sizes, int n_in,
                              void* d_out, int out_size, void* d_ws, size_t ws_size,
                              hipStream_t stream) {
  const float* obs     = (const float*)d_in[0];
  const float* conv1_w = (const float*)d_in[1];
  const float* conv1_b = (const float*)d_in[2];
  const float* conv2_w = (const float*)d_in[3];
  const float* conv2_b = (const float*)d_in[4];
  const float* conv3_w = (const float*)d_in[5];
  const float* conv3_b = (const float*)d_in[6];
  const float* fc1_w   = (const float*)d_in[7];
  const float* fc1_b   = (const float*)d_in[8];
  const float* fc2_w   = (const float*)d_in[9];
  const float* fc2_b   = (const float*)d_in[10];
  const float* gate_w  = (const float*)d_in[11];
  const float* gate_b  = (const float*)d_in[12];
  const float* exp_w1  = (const float*)d_in[13];
  const float* exp_b1  = (const float*)d_in[14];
  const float* exp_w2  = (const float*)d_in[15];
  const float* exp_b2  = (const float*)d_in[16];

  char* ws = (char*)d_ws;
  const size_t MB = 1ull << 20;
  const size_t KB = 1ull << 10;
  _Float16*       act1h = (_Float16*)(ws);                 // 32 MB [256][64][64][16] NHWC f16
  _Float16*       act1l = (_Float16*)(ws + 32 * MB);
  _Float16*       act2h = (_Float16*)(ws + 64 * MB);       // 64 MB [256][64][64][32] NHWC f16
  _Float16*       act2l = (_Float16*)(ws + 128 * MB);
  unsigned short* act3h = (unsigned short*)(ws + 192 * MB); // 128 MB [256][64][4096] NCHW bf16
  unsigned short* act3l = (unsigned short*)(ws + 320 * MB); // 128 MB bf16 lo (unscaled)
  float*    P     = (float*)(ws);                          // 64 MB [64][256][1024]
  _Float16* wp2h  = (_Float16*)(ws + 448 * MB);
  _Float16* wp2l  = (_Float16*)(ws + 448 * MB + 64 * KB);
  _Float16* wp3h  = (_Float16*)(ws + 448 * MB + 128 * KB);
  _Float16* wp3l  = (_Float16*)(ws + 448 * MB + 192 * KB);
  float*    s2    = (float*)(ws + 448 * MB + 256 * KB);
  int*      topi  = (int*)(ws + 448 * MB + 512 * KB);
  float*    topv  = (float*)(ws + 448 * MB + 516 * KB);
  float*    out   = (float*)d_out;

  prepack_w<<<(32 * 192 + 255) / 256, 256, 0, stream>>>(conv2_w, wp2h, wp2l, 32, 16, 64);
  prepack_w<<<(64 * 288 + 255) / 256, 256, 0, stream>>>(conv3_w, wp3h, wp3l, 64, 32, 96);

  conv1_k<<<dim3(16, 256), 256, 0, stream>>>(obs, conv1_w, conv1_b, act1h, act1l);
  conv_mfma<16, 32, false><<<dim3(32, 256), 256, 0, stream>>>(act1h, act1l, wp2h, wp2l, conv2_b,
                                                              (unsigned short*)act2h, (unsigned short*)act2l);
  conv_mfma<32, 64, true ><<<dim3(32, 256), 256, 0, stream>>>(act2h, act2l, wp3h, wp3l, conv3_b,
                                                              act3h, act3l);

  fc1_gemm_v14<<<dim3(64, 4), 512, 0, stream>>>(act3h, act3l, fc1_w, P);
  fc1r_fc2_gate<<<256, 256, 0, stream>>>(P, fc1_b, fc2_w, fc2_b, gate_w, gate_b,
                                         s2, out + 256 * 18, topi, topv);
  expert_k<<<256, 256, 0, stream>>>(s2, exp_w1, exp_b1, exp_w2, exp_b2, topi, topv, out);
}